// Round 13
// baseline (160.535 us; speedup 1.0000x reference)
//
#include <hip/hip_runtime.h>
#include <hip/hip_bf16.h>

#define NN 16384
#define SIZE 256
#define DISTD 64
#define KNBR 16
#define HEADS 8
#define HIDDEN 512
#define HA 256
#define SCALE 0.17677669529663687f

typedef __bf16 bf16;
typedef bf16 bf16x2 __attribute__((ext_vector_type(2)));
typedef bf16 bf16x4 __attribute__((ext_vector_type(4)));
typedef bf16 bf16x8 __attribute__((ext_vector_type(8)));
typedef float f32x4 __attribute__((ext_vector_type(4)));

__device__ __forceinline__ void gload16(const void* g, void* l) {
    __builtin_amdgcn_global_load_lds(
        (const __attribute__((address_space(1))) unsigned int*)g,
        (__attribute__((address_space(3))) unsigned int*)l, 16, 0, 0);
}

// ---------------------------------------------------------------------------
// 2-phase double-buffered 128x128 GEMM, BK = 32*SUBS (SUBS=2 proven r8).
// ---------------------------------------------------------------------------
template<bool BIAS, bool RELU_OUT, bool RESID, typename OutT, int SUBS>
__global__ __launch_bounds__(256) void gemm128(
    const bf16* __restrict__ A, const bf16* __restrict__ BT,
    const float* __restrict__ bias, const float* __restrict__ resid,
    OutT* __restrict__ C, int M, int N, int K)
{
    __shared__ alignas(16) bf16 As[2][SUBS][128][32];
    __shared__ alignas(16) bf16 Bs[2][SUBS][128][32];

    const int t = threadIdx.x;
    const int w = t >> 6, l = t & 63;
    const int bm = blockIdx.y * 128, bn = blockIdx.x * 128;
    const int wr = (w >> 1) * 64, wc = (w & 1) * 64;
    const int BK = 32 * SUBS;

    f32x4 acc[4][4] = {};

    const bf16* ag = A  + (size_t)(bm + (t >> 2)) * K + (t & 3) * 8;
    const bf16* bg = BT + (size_t)(bn + (t >> 2)) * K + (t & 3) * 8;

    auto STAGE = [&](int buf, int k0) {
        #pragma unroll
        for (int s = 0; s < SUBS; ++s) {
            bf16* asl = &As[buf][s][w << 4][0];
            bf16* bsl = &Bs[buf][s][w << 4][0];
            gload16(ag + k0 + s * 32, asl);
            gload16(ag + k0 + s * 32 + (size_t)64 * K, (char*)asl + 4096);
            gload16(bg + k0 + s * 32, bsl);
            gload16(bg + k0 + s * 32 + (size_t)64 * K, (char*)bsl + 4096);
        }
    };

    const int nt = K / BK;
    STAGE(0, 0);
    __syncthreads();

    for (int tt = 0; tt < nt; ++tt) {
        const int cur = tt & 1;
        if (tt + 1 < nt) STAGE(cur ^ 1, (tt + 1) * BK);

        #pragma unroll
        for (int s = 0; s < SUBS; ++s) {
            bf16x8 af[4], bfr[4];
            #pragma unroll
            for (int m = 0; m < 4; ++m)
                af[m] = *(const bf16x8*)&As[cur][s][wr + m * 16 + (l & 15)][(l >> 4) * 8];
            #pragma unroll
            for (int n2 = 0; n2 < 4; ++n2)
                bfr[n2] = *(const bf16x8*)&Bs[cur][s][wc + n2 * 16 + (l & 15)][(l >> 4) * 8];
            #pragma unroll
            for (int m = 0; m < 4; ++m)
                #pragma unroll
                for (int n2 = 0; n2 < 4; ++n2)
                    acc[m][n2] = __builtin_amdgcn_mfma_f32_16x16x32_bf16(
                        af[m], bfr[n2], acc[m][n2], 0, 0, 0);
        }
        __syncthreads();
    }

    #pragma unroll
    for (int m = 0; m < 4; ++m) {
        const int row = bm + wr + m * 16 + ((l >> 4) << 2);
        #pragma unroll
        for (int n2 = 0; n2 < 4; ++n2) {
            const int col = bn + wc + n2 * 16 + (l & 15);
            #pragma unroll
            for (int i = 0; i < 4; ++i) {
                float v = acc[m][n2][i];
                if (BIAS) v += bias[col];
                if (RESID) v += resid[(size_t)(row + i) * N + col];
                if (RELU_OUT) v = fmaxf(v, 0.f);
                C[(size_t)(row + i) * N + col] = (OutT)v;
            }
        }
    }
}

// ---------------------------------------------------------------------------
// Fused G1 + qcat dispatch (both K=256), BK=32 (r10-proven: 1280 blocks).
//  bx<4 : H0   = relu(frbf @ W0T + b0)            (bf16, ld 512)
//  bx>=4: qcat = fbf @ Wqcat_cols + bqcat          (bf16, ld 768, pre-scaled)
// ---------------------------------------------------------------------------
__global__ __launch_bounds__(256) void g1qcat_kernel(
    const bf16* __restrict__ fbf, const bf16* __restrict__ frbf,
    const bf16* __restrict__ W0T, const float* __restrict__ b0,
    const bf16* __restrict__ WqcatT, const float* __restrict__ bqcat,
    bf16* __restrict__ H0, bf16* __restrict__ qcat)
{
    __shared__ alignas(16) bf16 As[2][128][32];
    __shared__ alignas(16) bf16 Bs[2][128][32];

    const int bx = blockIdx.x, by = blockIdx.y;
    const bool isG1 = bx < 4;
    const int cx = bx - 4;
    const bf16* A  = isG1 ? frbf : fbf;
    const bf16* BT = isG1 ? (W0T + (size_t)bx * 128 * 256)
                          : (WqcatT + (size_t)cx * 128 * 256);
    const float* bias = isG1 ? (b0 + bx * 128) : (bqcat + cx * 128);
    const int K = 256;

    const int t = threadIdx.x;
    const int w = t >> 6, l = t & 63;
    const int bm = by * 128;
    const int wr = (w >> 1) * 64, wc = (w & 1) * 64;

    f32x4 acc[4][4] = {};

    const bf16* ag = A  + (size_t)(bm + (t >> 2)) * K + (t & 3) * 8;
    const bf16* bg = BT + (size_t)(t >> 2) * K + (t & 3) * 8;

    {
        bf16* asl = &As[0][w << 4][0];
        bf16* bsl = &Bs[0][w << 4][0];
        gload16(ag, asl);
        gload16(ag + (size_t)64 * K, (char*)asl + 4096);
        gload16(bg, bsl);
        gload16(bg + (size_t)64 * K, (char*)bsl + 4096);
    }
    __syncthreads();

    for (int tt = 0; tt < 8; ++tt) {
        const int cur = tt & 1;
        if (tt + 1 < 8) {
            const int k0 = (tt + 1) << 5;
            bf16* asl = &As[cur ^ 1][w << 4][0];
            bf16* bsl = &Bs[cur ^ 1][w << 4][0];
            gload16(ag + k0, asl);
            gload16(ag + k0 + (size_t)64 * K, (char*)asl + 4096);
            gload16(bg + k0, bsl);
            gload16(bg + k0 + (size_t)64 * K, (char*)bsl + 4096);
        }
        bf16x8 af[4], bfr[4];
        #pragma unroll
        for (int m = 0; m < 4; ++m)
            af[m] = *(const bf16x8*)&As[cur][wr + m * 16 + (l & 15)][(l >> 4) * 8];
        #pragma unroll
        for (int n2 = 0; n2 < 4; ++n2)
            bfr[n2] = *(const bf16x8*)&Bs[cur][wc + n2 * 16 + (l & 15)][(l >> 4) * 8];
        #pragma unroll
        for (int m = 0; m < 4; ++m)
            #pragma unroll
            for (int n2 = 0; n2 < 4; ++n2)
                acc[m][n2] = __builtin_amdgcn_mfma_f32_16x16x32_bf16(
                    af[m], bfr[n2], acc[m][n2], 0, 0, 0);
        __syncthreads();
    }

    #pragma unroll
    for (int m = 0; m < 4; ++m) {
        const int lrow = wr + m * 16 + ((l >> 4) << 2);
        #pragma unroll
        for (int n2 = 0; n2 < 4; ++n2) {
            const int lcol = wc + n2 * 16 + (l & 15);
            #pragma unroll
            for (int i = 0; i < 4; ++i) {
                float v = acc[m][n2][i] + bias[lcol];
                const size_t row = bm + lrow + i;
                if (isG1) {
                    H0[row * 512 + bx * 128 + lcol] = (bf16)fmaxf(v, 0.f);
                } else {
                    qcat[row * 768 + cx * 128 + lcol] = (bf16)v;
                }
            }
        }
    }
}

// ---------------------------------------------------------------------------
// Fused prep with COALESCED LDS-tiled transposes (r10-proven).
// ---------------------------------------------------------------------------
__global__ __launch_bounds__(256) void prep_all(
    const float* __restrict__ features,
    const float* __restrict__ W0, const float* __restrict__ W1,
    const float* __restrict__ W2, const float* __restrict__ Wq,
    const float* __restrict__ bq, const float* __restrict__ Wk,
    const float* __restrict__ Wv, const float* __restrict__ Wo,
    const float* __restrict__ bo, const float* __restrict__ bv,
    bf16* __restrict__ fbf, bf16* __restrict__ frbf,
    bf16* __restrict__ W0T, bf16* __restrict__ W1T, bf16* __restrict__ W2T,
    bf16* __restrict__ WkvT, bf16* __restrict__ WqcatT, bf16* __restrict__ WstackT,
    float* __restrict__ bqcat, float* __restrict__ biaso)
{
    __shared__ float tl[32][33];
    const int t = threadIdx.x;

    if (blockIdx.x < 4096) {
        int id = blockIdx.x * 256 + t;
        float4 v = ((const float4*)features)[id];
        bf16x4 a, r;
        a[0] = (bf16)v.x; a[1] = (bf16)v.y; a[2] = (bf16)v.z; a[3] = (bf16)v.w;
        r[0] = (bf16)fmaxf(v.x, 0.f); r[1] = (bf16)fmaxf(v.y, 0.f);
        r[2] = (bf16)fmaxf(v.z, 0.f); r[3] = (bf16)fmaxf(v.w, 0.f);
        ((bf16x4*)fbf)[id] = a; ((bf16x4*)frbf)[id] = r;
        return;
    }
    if (blockIdx.x < 4864) {
        int tile = blockIdx.x - 4096;
        const float* src; bf16* dst; int srcLd, dstLd, tpr; float scl = 1.f;
        if (tile < 128)      { src = W0; srcLd = 512; tpr = 16; dst = W0T;  dstLd = 256; }
        else if (tile < 384) { tile -= 128; src = W1; srcLd = 512; tpr = 16; dst = W1T;  dstLd = 512; }
        else if (tile < 512) { tile -= 384; src = W2; srcLd = 256; tpr = 8;  dst = W2T;  dstLd = 512; }
        else if (tile < 576) { tile -= 512; src = Wk; srcLd = 256; tpr = 8;  dst = WkvT; dstLd = 256; }
        else if (tile < 640) { tile -= 576; src = Wv; srcLd = 256; tpr = 8;  dst = WkvT + 65536; dstLd = 256; }
        else if (tile < 704) { tile -= 640; src = Wq; srcLd = 256; tpr = 8;  dst = WqcatT; dstLd = 256; scl = SCALE; }
        else                 { tile -= 704; src = Wo; srcLd = 256; tpr = 8;  dst = WstackT; dstLd = 768; }
        const int tr = tile / tpr, tc = tile % tpr;
        const int x = t & 31, y0 = t >> 5;
        #pragma unroll
        for (int p = 0; p < 4; ++p) {
            int y = y0 + 8 * p;
            tl[y][x] = src[(size_t)(tr * 32 + y) * srcLd + tc * 32 + x];
        }
        __syncthreads();
        #pragma unroll
        for (int p = 0; p < 4; ++p) {
            int a2 = y0 + 8 * p;
            dst[(size_t)(tc * 32 + a2) * dstLd + tr * 32 + x] = (bf16)(tl[x][a2] * scl);
        }
        return;
    }
    if (blockIdx.x < 5376) {
        int id = (blockIdx.x - 4864) * 256 + t;
        int hd = id >> 8, c = id & 255;
        int h = hd >> 6, d = hd & 63;
        float s = 0.f;
        #pragma unroll
        for (int a = 0; a < 32; ++a)
            s += Wq[(size_t)c * 256 + h * 32 + a] * Wk[(size_t)(256 + d) * 256 + h * 32 + a];
        WqcatT[65536 + id] = (bf16)(s * SCALE);
        return;
    }
    if (blockIdx.x < 5888) {
        int id = (blockIdx.x - 5376) * 256 + t;
        int r2 = id >> 8, col = id & 255;
        int h = r2 >> 6, d = r2 & 63;
        float s = 0.f;
        #pragma unroll
        for (int a = 0; a < 32; ++a)
            s += Wv[(size_t)(256 + d) * 256 + h * 32 + a] * Wo[(size_t)(h * 32 + a) * 256 + col];
        WstackT[(size_t)col * 768 + 256 + r2] = (bf16)s;
        return;
    }
    if (blockIdx.x == 5888) {
        #pragma unroll
        for (int rep = 0; rep < 3; ++rep) {
            int idx = rep * 256 + t;
            if (idx >= 768) break;
            float s;
            if (idx < 256) s = bq[idx];
            else {
                int hd = idx - 256, h = hd >> 6, d = hd & 63;
                s = 0.f;
                #pragma unroll
                for (int a = 0; a < 32; ++a)
                    s += bq[h * 32 + a] * Wk[(size_t)(256 + d) * 256 + h * 32 + a];
            }
            bqcat[idx] = s * SCALE;
        }
        return;
    }
    {   // biaso = bo + bv @ Wo
        float s = bo[t];
        for (int u = 0; u < 256; ++u) s += bv[u] * Wo[(size_t)u * 256 + t];
        biaso[t] = s;
    }
}

// ---------------------------------------------------------------------------
// Attention: r9 per-node structure (proven 52 µs), TWO nodes per 512-thread
// block. nn = t>>8 selects node; tt = t&255 runs the identical per-node code.
// Waves 0-3 serve node 0, waves 4-7 node 1 (all shuffles stay in-wave).
// Doubles independent memory streams per CU (occupancy cap 32 waves/CU).
// ---------------------------------------------------------------------------
__global__ __launch_bounds__(512) void attn_kernel(
    const bf16* __restrict__ qcat,      // [NN, 768]  (q | qproj), pre-scaled
    const bf16* __restrict__ localKV,   // [NN, 512]  (K | V)
    const float* __restrict__ dist,     // [NN, 16, 64]
    const int*  __restrict__ structure, // [NN, 16]
    bf16* __restrict__ concat)          // [NN, 768]
{
    const int nn = threadIdx.x >> 8;            // node slot 0/1
    const int tt = threadIdx.x & 255;           // per-node thread id
    const long n = (long)blockIdx.x * 2 + nn;
    const int h = tt >> 5, j = (tt >> 1) & 15, part = tt & 1;

    __shared__ float dist_s[2][16][68];
    __shared__ bf16  V_s[2][16][264];
    __shared__ float attn_s[2][8][16];
    __shared__ int   s_s[2][16];

    {
        const float* dp = dist + n * (KNBR * DISTD);
        #pragma unroll
        for (int i = 0; i < 4; ++i) {
            int e = i * 256 + tt;
            dist_s[nn][e >> 6][e & 63] = dp[e];
        }
    }
    if (tt < 16) s_s[nn][tt] = structure[n * KNBR + tt];
    __syncthreads();

    #pragma unroll
    for (int pass = 0; pass < 2; ++pass) {
        int idx = pass * 256 + tt;
        int row = idx >> 5, chunk = idx & 31;
        bf16x8 v = *(const bf16x8*)(localKV + (long)s_s[nn][row] * 512 + 256 + chunk * 8);
        *(bf16x8*)&V_s[nn][row][chunk * 8] = v;
    }

    const bf16* qp_q = qcat + n * 768 + h * 32 + part * 16;
    bf16x8 qa = *(const bf16x8*)qp_q;
    bf16x8 qb = *(const bf16x8*)(qp_q + 8);
    const bf16* qp_p = qcat + n * 768 + 256 + h * 64 + part * 32;
    bf16x8 p[4];
    p[0] = *(const bf16x8*)qp_p;
    p[1] = *(const bf16x8*)(qp_p + 8);
    p[2] = *(const bf16x8*)(qp_p + 16);
    p[3] = *(const bf16x8*)(qp_p + 24);
    const bf16* kp = localKV + (long)s_s[nn][j] * 512 + h * 32 + part * 16;
    bf16x8 ka = *(const bf16x8*)kp;
    bf16x8 kb = *(const bf16x8*)(kp + 8);

    float sc = 0.f;
    #pragma unroll
    for (int i = 0; i < 8; ++i)
        sc += (float)qa[i] * (float)ka[i] + (float)qb[i] * (float)kb[i];

    const int dbase = part * 32;
    #pragma unroll
    for (int i = 0; i < 4; ++i) {
        const f32x4 a4 = *(const f32x4*)&dist_s[nn][j][dbase + 8 * i];
        const f32x4 b4 = *(const f32x4*)&dist_s[nn][j][dbase + 8 * i + 4];
        sc += a4[0] * (float)p[i][0] + a4[1] * (float)p[i][1]
            + a4[2] * (float)p[i][2] + a4[3] * (float)p[i][3]
            + b4[0] * (float)p[i][4] + b4[1] * (float)p[i][5]
            + b4[2] * (float)p[i][6] + b4[3] * (float)p[i][7];
    }

    sc += __shfl_xor(sc, 1);           // full (pre-scaled) score
    float m = sc;
    m = fmaxf(m, __shfl_xor(m, 2));
    m = fmaxf(m, __shfl_xor(m, 4));
    m = fmaxf(m, __shfl_xor(m, 8));
    m = fmaxf(m, __shfl_xor(m, 16));
    float e = __expf(sc - m);
    float sum = e;
    sum += __shfl_xor(sum, 2);
    sum += __shfl_xor(sum, 4);
    sum += __shfl_xor(sum, 8);
    sum += __shfl_xor(sum, 16);
    float attn = e / sum;
    if (!part) attn_s[nn][h][j] = attn;
    __syncthreads();

    if (tt < 128) {
        // o: col pair (2tt, 2tt+1)
        const int c0 = tt * 2;
        const int hh = tt >> 4;
        float a0 = 0.f, a1 = 0.f;
        #pragma unroll
        for (int j2 = 0; j2 < 16; ++j2) {
            float wgt = attn_s[nn][hh][j2];
            bf16x2 pv = *(const bf16x2*)&V_s[nn][j2][c0];
            a0 += wgt * (float)pv[0];
            a1 += wgt * (float)pv[1];
        }
        bf16x2 o2; o2[0] = (bf16)a0; o2[1] = (bf16)a1;
        *(bf16x2*)&concat[n * 768 + c0] = o2;
    } else {
        // wd: 4 outputs (u*4 .. u*4+3)
        const int u = tt - 128;
        const int base = u * 4;
        const int h3 = u >> 4, d3 = (u & 15) * 4;
        f32x4 acc4 = {};
        #pragma unroll
        for (int j2 = 0; j2 < 16; ++j2) {
            float wgt = attn_s[nn][h3][j2];
            const f32x4 dv = *(const f32x4*)&dist_s[nn][j2][d3];
            acc4 += wgt * dv;
        }
        bf16x4 o4;
        #pragma unroll
        for (int i = 0; i < 4; ++i) o4[i] = (bf16)acc4[i];
        *(bf16x4*)&concat[n * 768 + 256 + base] = o4;
    }
}

// ---------------------------------------------------------------------------
extern "C" void kernel_launch(void* const* d_in, const int* in_sizes, int n_in,
                              void* d_out, int out_size, void* d_ws, size_t ws_size,
                              hipStream_t stream)
{
    const float* features = (const float*)d_in[0];
    const float* dist     = (const float*)d_in[1];
    const int*   structure= (const int*)d_in[2];
    const float* W0 = (const float*)d_in[3];
    const float* b0 = (const float*)d_in[4];
    const float* W1 = (const float*)d_in[5];
    const float* b1 = (const float*)d_in[6];
    const float* W2 = (const float*)d_in[7];
    const float* b2 = (const float*)d_in[8];
    const float* Wq = (const float*)d_in[9];
    const float* bq = (const float*)d_in[10];
    const float* Wk = (const float*)d_in[11];
    // d_in[12] = bk : dropped exactly (softmax-invariant per-head shift)
    const float* Wv = (const float*)d_in[13];
    const float* bv = (const float*)d_in[14];
    const float* Wo = (const float*)d_in[15];
    const float* bo = (const float*)d_in[16];
    float* out = (float*)d_out;

    const size_t MB = 1u << 20;
    char* w = (char*)d_ws;
    // live intervals:
    bf16*  fbf     = (bf16*)(w + 0 * MB);    // [0,8)    prep -> g1qcat
    bf16*  local_b = (bf16*)(w + 0 * MB);    // [0,8)    G3 -> KV     (fbf dead)
    bf16*  frbf    = (bf16*)(w + 8 * MB);    // [8,16)   prep -> g1qcat
    bf16*  localKV = (bf16*)(w + 8 * MB);    // [8,24)   KV -> attn   (frbf/H0 dead)
    bf16*  H0      = (bf16*)(w + 16 * MB);   // [16,32)  g1qcat -> G2
    bf16*  qcat    = (bf16*)(w + 32 * MB);   // [32,56)  g1qcat -> attn
    bf16*  H1      = (bf16*)(w + 56 * MB);   // [56,72)  G2 -> G3
    bf16*  concat  = (bf16*)(w + 56 * MB);   // [56,80)  attn -> final (H1 dead)
    char*  wb      = w + 80 * MB;            // weights: prep -> final
    bf16*  W0T     = (bf16*)(wb + 0);
    bf16*  W1T     = (bf16*)(wb + 262144);
    bf16*  W2T     = (bf16*)(wb + 786432);
    bf16*  WkvT    = (bf16*)(wb + 1048576);
    bf16*  WqcatT  = (bf16*)(wb + 1310720);
    bf16*  WstackT = (bf16*)(wb + 1703936);
    float* bqcat   = (float*)(wb + 2097152);
    float* biaso   = (float*)(wb + 2100224);

    dim3 blk(256);

    prep_all<<<dim3(5890), blk, 0, stream>>>(
        features, W0, W1, W2, Wq, bq, Wk, Wv, Wo, bo, bv,
        fbf, frbf, W0T, W1T, W2T, WkvT, WqcatT, WstackT, bqcat, biaso);

    // fused: H0 = relu(relu(f)@W0+b0); qcat = f@Wqcat+bqcat (pre-scaled), BK=32
    g1qcat_kernel<<<dim3(10, 128), blk, 0, stream>>>(
        fbf, frbf, W0T, b0, WqcatT, bqcat, H0, qcat);

    // W1: H1 = relu(H0@W1+b1)          (BK=64: 512 blocks, 2/CU)
    gemm128<true,  true,  false, bf16, 2><<<dim3(4, 128), blk, 0, stream>>>(
        H0, W1T, b1, nullptr, H1, NN, 512, 512);
    // W2: local = relu(H1@W2+b2)       (256 blocks)
    gemm128<true,  true,  false, bf16, 2><<<dim3(2, 128), blk, 0, stream>>>(
        H1, W2T, b2, nullptr, local_b, NN, 256, 512);
    // KV: localKV = local @ [Wk|Wv]    (512 blocks)
    gemm128<false, false, false, bf16, 2><<<dim3(4, 128), blk, 0, stream>>>(
        local_b, WkvT, nullptr, nullptr, localKV, NN, 512, 256);

    attn_kernel<<<dim3(NN / 2), dim3(512), 0, stream>>>(
        qcat, localKV, dist, structure, concat);

    // out = concat @ [Wo ; U] + (bo + bv@Wo) + features  (256 blocks)
    gemm128<true,  false, true,  float, 2><<<dim3(2, 128), blk, 0, stream>>>(
        concat, WstackT, biaso, features, out, NN, 256, 768);
}

// Round 14
// 158.014 us; speedup vs baseline: 1.0160x; 1.0160x over previous
//
#include <hip/hip_runtime.h>
#include <hip/hip_bf16.h>

#define NN 16384
#define SIZE 256
#define DISTD 64
#define KNBR 16
#define HEADS 8
#define HIDDEN 512
#define HA 256
#define SCALE 0.17677669529663687f

typedef __bf16 bf16;
typedef bf16 bf16x2 __attribute__((ext_vector_type(2)));
typedef bf16 bf16x4 __attribute__((ext_vector_type(4)));
typedef bf16 bf16x8 __attribute__((ext_vector_type(8)));
typedef float f32x4 __attribute__((ext_vector_type(4)));

__device__ __forceinline__ void gload16(const void* g, void* l) {
    __builtin_amdgcn_global_load_lds(
        (const __attribute__((address_space(1))) unsigned int*)g,
        (__attribute__((address_space(3))) unsigned int*)l, 16, 0, 0);
}

// packed bf16 relu on a dword (2 lanes): negative lanes -> 0x0000.
__device__ __forceinline__ unsigned int relu2bf(unsigned int x) {
    unsigned int s = x & 0x80008000u;
    unsigned int mask = (s - (s >> 15)) | s;   // 0xFFFF in negative lanes
    return x & ~mask;
}

// ---------------------------------------------------------------------------
// 2-phase double-buffered 128x128 GEMM, BK = 32*SUBS (SUBS=2 proven r8).
// ---------------------------------------------------------------------------
template<bool BIAS, bool RELU_OUT, bool RESID, typename OutT, int SUBS>
__global__ __launch_bounds__(256) void gemm128(
    const bf16* __restrict__ A, const bf16* __restrict__ BT,
    const float* __restrict__ bias, const float* __restrict__ resid,
    OutT* __restrict__ C, int M, int N, int K)
{
    __shared__ alignas(16) bf16 As[2][SUBS][128][32];
    __shared__ alignas(16) bf16 Bs[2][SUBS][128][32];

    const int t = threadIdx.x;
    const int w = t >> 6, l = t & 63;
    const int bm = blockIdx.y * 128, bn = blockIdx.x * 128;
    const int wr = (w >> 1) * 64, wc = (w & 1) * 64;
    const int BK = 32 * SUBS;

    f32x4 acc[4][4] = {};

    const bf16* ag = A  + (size_t)(bm + (t >> 2)) * K + (t & 3) * 8;
    const bf16* bg = BT + (size_t)(bn + (t >> 2)) * K + (t & 3) * 8;

    auto STAGE = [&](int buf, int k0) {
        #pragma unroll
        for (int s = 0; s < SUBS; ++s) {
            bf16* asl = &As[buf][s][w << 4][0];
            bf16* bsl = &Bs[buf][s][w << 4][0];
            gload16(ag + k0 + s * 32, asl);
            gload16(ag + k0 + s * 32 + (size_t)64 * K, (char*)asl + 4096);
            gload16(bg + k0 + s * 32, bsl);
            gload16(bg + k0 + s * 32 + (size_t)64 * K, (char*)bsl + 4096);
        }
    };

    const int nt = K / BK;
    STAGE(0, 0);
    __syncthreads();

    for (int tt = 0; tt < nt; ++tt) {
        const int cur = tt & 1;
        if (tt + 1 < nt) STAGE(cur ^ 1, (tt + 1) * BK);

        #pragma unroll
        for (int s = 0; s < SUBS; ++s) {
            bf16x8 af[4], bfr[4];
            #pragma unroll
            for (int m = 0; m < 4; ++m)
                af[m] = *(const bf16x8*)&As[cur][s][wr + m * 16 + (l & 15)][(l >> 4) * 8];
            #pragma unroll
            for (int n2 = 0; n2 < 4; ++n2)
                bfr[n2] = *(const bf16x8*)&Bs[cur][s][wc + n2 * 16 + (l & 15)][(l >> 4) * 8];
            #pragma unroll
            for (int m = 0; m < 4; ++m)
                #pragma unroll
                for (int n2 = 0; n2 < 4; ++n2)
                    acc[m][n2] = __builtin_amdgcn_mfma_f32_16x16x32_bf16(
                        af[m], bfr[n2], acc[m][n2], 0, 0, 0);
        }
        __syncthreads();
    }

    #pragma unroll
    for (int m = 0; m < 4; ++m) {
        const int row = bm + wr + m * 16 + ((l >> 4) << 2);
        #pragma unroll
        for (int n2 = 0; n2 < 4; ++n2) {
            const int col = bn + wc + n2 * 16 + (l & 15);
            #pragma unroll
            for (int i = 0; i < 4; ++i) {
                float v = acc[m][n2][i];
                if (BIAS) v += bias[col];
                if (RESID) v += resid[(size_t)(row + i) * N + col];
                if (RELU_OUT) v = fmaxf(v, 0.f);
                C[(size_t)(row + i) * N + col] = (OutT)v;
            }
        }
    }
}

// ---------------------------------------------------------------------------
// Fused G1 + qcat dispatch (both K=256), BK=32. grid (10,128):
//  bx<4 : H0   = relu(relu(f) @ W0T + b0)   — relu on A applied IN-FRAGMENT
//  bx>=4: qcat = f @ Wqcat_cols + bqcat      (bf16, ld 768, pre-scaled)
// Both paths read the same fbf stream (frbf buffer eliminated).
// ---------------------------------------------------------------------------
__global__ __launch_bounds__(256) void g1qcat_kernel(
    const bf16* __restrict__ fbf,
    const bf16* __restrict__ W0T, const float* __restrict__ b0,
    const bf16* __restrict__ WqcatT, const float* __restrict__ bqcat,
    bf16* __restrict__ H0, bf16* __restrict__ qcat)
{
    __shared__ alignas(16) bf16 As[2][128][32];
    __shared__ alignas(16) bf16 Bs[2][128][32];

    const int bx = blockIdx.x, by = blockIdx.y;
    const bool isG1 = bx < 4;
    const int cx = bx - 4;
    const bf16* BT = isG1 ? (W0T + (size_t)bx * 128 * 256)
                          : (WqcatT + (size_t)cx * 128 * 256);
    const float* bias = isG1 ? (b0 + bx * 128) : (bqcat + cx * 128);
    const int K = 256;

    const int t = threadIdx.x;
    const int w = t >> 6, l = t & 63;
    const int bm = by * 128;
    const int wr = (w >> 1) * 64, wc = (w & 1) * 64;

    f32x4 acc[4][4] = {};

    const bf16* ag = fbf + (size_t)(bm + (t >> 2)) * K + (t & 3) * 8;
    const bf16* bg = BT  + (size_t)(t >> 2) * K + (t & 3) * 8;

    {
        bf16* asl = &As[0][w << 4][0];
        bf16* bsl = &Bs[0][w << 4][0];
        gload16(ag, asl);
        gload16(ag + (size_t)64 * K, (char*)asl + 4096);
        gload16(bg, bsl);
        gload16(bg + (size_t)64 * K, (char*)bsl + 4096);
    }
    __syncthreads();

    for (int tt = 0; tt < 8; ++tt) {
        const int cur = tt & 1;
        if (tt + 1 < 8) {
            const int k0 = (tt + 1) << 5;
            bf16* asl = &As[cur ^ 1][w << 4][0];
            bf16* bsl = &Bs[cur ^ 1][w << 4][0];
            gload16(ag + k0, asl);
            gload16(ag + k0 + (size_t)64 * K, (char*)asl + 4096);
            gload16(bg + k0, bsl);
            gload16(bg + k0 + (size_t)64 * K, (char*)bsl + 4096);
        }
        bf16x8 af[4], bfr[4];
        #pragma unroll
        for (int m = 0; m < 4; ++m)
            af[m] = *(const bf16x8*)&As[cur][wr + m * 16 + (l & 15)][(l >> 4) * 8];
        if (isG1) {     // uniform branch: relu(A) in-register (exact vs frbf)
            #pragma unroll
            for (int m = 0; m < 4; ++m) {
                unsigned int* u = (unsigned int*)&af[m];
                #pragma unroll
                for (int q2 = 0; q2 < 4; ++q2) u[q2] = relu2bf(u[q2]);
            }
        }
        #pragma unroll
        for (int n2 = 0; n2 < 4; ++n2)
            bfr[n2] = *(const bf16x8*)&Bs[cur][wc + n2 * 16 + (l & 15)][(l >> 4) * 8];
        #pragma unroll
        for (int m = 0; m < 4; ++m)
            #pragma unroll
            for (int n2 = 0; n2 < 4; ++n2)
                acc[m][n2] = __builtin_amdgcn_mfma_f32_16x16x32_bf16(
                    af[m], bfr[n2], acc[m][n2], 0, 0, 0);
        __syncthreads();
    }

    #pragma unroll
    for (int m = 0; m < 4; ++m) {
        const int lrow = wr + m * 16 + ((l >> 4) << 2);
        #pragma unroll
        for (int n2 = 0; n2 < 4; ++n2) {
            const int lcol = wc + n2 * 16 + (l & 15);
            #pragma unroll
            for (int i = 0; i < 4; ++i) {
                float v = acc[m][n2][i] + bias[lcol];
                const size_t row = bm + lrow + i;
                if (isG1) {
                    H0[row * 512 + bx * 128 + lcol] = (bf16)fmaxf(v, 0.f);
                } else {
                    qcat[row * 768 + cx * 128 + lcol] = (bf16)v;
                }
            }
        }
    }
}

// ---------------------------------------------------------------------------
// Fused prep with COALESCED LDS-tiled transposes (r10-proven); frbf dropped.
// ---------------------------------------------------------------------------
__global__ __launch_bounds__(256) void prep_all(
    const float* __restrict__ features,
    const float* __restrict__ W0, const float* __restrict__ W1,
    const float* __restrict__ W2, const float* __restrict__ Wq,
    const float* __restrict__ bq, const float* __restrict__ Wk,
    const float* __restrict__ Wv, const float* __restrict__ Wo,
    const float* __restrict__ bo, const float* __restrict__ bv,
    bf16* __restrict__ fbf,
    bf16* __restrict__ W0T, bf16* __restrict__ W1T, bf16* __restrict__ W2T,
    bf16* __restrict__ WkvT, bf16* __restrict__ WqcatT, bf16* __restrict__ WstackT,
    float* __restrict__ bqcat, float* __restrict__ biaso)
{
    __shared__ float tl[32][33];
    const int t = threadIdx.x;

    if (blockIdx.x < 4096) {
        int id = blockIdx.x * 256 + t;
        float4 v = ((const float4*)features)[id];
        bf16x4 a;
        a[0] = (bf16)v.x; a[1] = (bf16)v.y; a[2] = (bf16)v.z; a[3] = (bf16)v.w;
        ((bf16x4*)fbf)[id] = a;
        return;
    }
    if (blockIdx.x < 4864) {
        int tile = blockIdx.x - 4096;
        const float* src; bf16* dst; int srcLd, dstLd, tpr; float scl = 1.f;
        if (tile < 128)      { src = W0; srcLd = 512; tpr = 16; dst = W0T;  dstLd = 256; }
        else if (tile < 384) { tile -= 128; src = W1; srcLd = 512; tpr = 16; dst = W1T;  dstLd = 512; }
        else if (tile < 512) { tile -= 384; src = W2; srcLd = 256; tpr = 8;  dst = W2T;  dstLd = 512; }
        else if (tile < 576) { tile -= 512; src = Wk; srcLd = 256; tpr = 8;  dst = WkvT; dstLd = 256; }
        else if (tile < 640) { tile -= 576; src = Wv; srcLd = 256; tpr = 8;  dst = WkvT + 65536; dstLd = 256; }
        else if (tile < 704) { tile -= 640; src = Wq; srcLd = 256; tpr = 8;  dst = WqcatT; dstLd = 256; scl = SCALE; }
        else                 { tile -= 704; src = Wo; srcLd = 256; tpr = 8;  dst = WstackT; dstLd = 768; }
        const int tr = tile / tpr, tc = tile % tpr;
        const int x = t & 31, y0 = t >> 5;
        #pragma unroll
        for (int p = 0; p < 4; ++p) {
            int y = y0 + 8 * p;
            tl[y][x] = src[(size_t)(tr * 32 + y) * srcLd + tc * 32 + x];
        }
        __syncthreads();
        #pragma unroll
        for (int p = 0; p < 4; ++p) {
            int a2 = y0 + 8 * p;
            dst[(size_t)(tc * 32 + a2) * dstLd + tr * 32 + x] = (bf16)(tl[x][a2] * scl);
        }
        return;
    }
    if (blockIdx.x < 5376) {
        int id = (blockIdx.x - 4864) * 256 + t;
        int hd = id >> 8, c = id & 255;
        int h = hd >> 6, d = hd & 63;
        float s = 0.f;
        #pragma unroll
        for (int a = 0; a < 32; ++a)
            s += Wq[(size_t)c * 256 + h * 32 + a] * Wk[(size_t)(256 + d) * 256 + h * 32 + a];
        WqcatT[65536 + id] = (bf16)(s * SCALE);
        return;
    }
    if (blockIdx.x < 5888) {
        int id = (blockIdx.x - 5376) * 256 + t;
        int r2 = id >> 8, col = id & 255;
        int h = r2 >> 6, d = r2 & 63;
        float s = 0.f;
        #pragma unroll
        for (int a = 0; a < 32; ++a)
            s += Wv[(size_t)(256 + d) * 256 + h * 32 + a] * Wo[(size_t)(h * 32 + a) * 256 + col];
        WstackT[(size_t)col * 768 + 256 + r2] = (bf16)s;
        return;
    }
    if (blockIdx.x == 5888) {
        #pragma unroll
        for (int rep = 0; rep < 3; ++rep) {
            int idx = rep * 256 + t;
            if (idx >= 768) break;
            float s;
            if (idx < 256) s = bq[idx];
            else {
                int hd = idx - 256, h = hd >> 6, d = hd & 63;
                s = 0.f;
                #pragma unroll
                for (int a = 0; a < 32; ++a)
                    s += bq[h * 32 + a] * Wk[(size_t)(256 + d) * 256 + h * 32 + a];
            }
            bqcat[idx] = s * SCALE;
        }
        return;
    }
    {   // biaso = bo + bv @ Wo
        float s = bo[t];
        for (int u = 0; u < 256; ++u) s += bv[u] * Wo[(size_t)u * 256 + t];
        biaso[t] = s;
    }
}

// ---------------------------------------------------------------------------
// Attention: EXACT r12 structure (best measured: 159.3 total / ~52 µs attn).
// ---------------------------------------------------------------------------
__global__ __launch_bounds__(256) void attn_kernel(
    const bf16* __restrict__ qcat,      // [NN, 768]  (q | qproj), pre-scaled
    const bf16* __restrict__ localKV,   // [NN, 512]  (K | V)
    const float* __restrict__ dist,     // [NN, 16, 64]
    const int*  __restrict__ structure, // [NN, 16]
    bf16* __restrict__ concat)          // [NN, 768]
{
    const int n = blockIdx.x;
    const int t = threadIdx.x;
    const int h = t >> 5, j = (t >> 1) & 15, part = t & 1;

    __shared__ float dist_s[16][68];
    __shared__ bf16  V_s[16][264];
    __shared__ float attn_s[8][16];
    __shared__ int   s_s[16];

    {
        const float* dp = dist + (long)n * (KNBR * DISTD);
        #pragma unroll
        for (int i = 0; i < 4; ++i) {
            int e = i * 256 + t;
            dist_s[e >> 6][e & 63] = dp[e];
        }
    }
    if (t < 16) s_s[t] = structure[(long)n * KNBR + t];
    __syncthreads();

    #pragma unroll
    for (int pass = 0; pass < 2; ++pass) {
        int idx = pass * 256 + t;
        int row = idx >> 5, chunk = idx & 31;
        bf16x8 v = *(const bf16x8*)(localKV + (long)s_s[row] * 512 + 256 + chunk * 8);
        *(bf16x8*)&V_s[row][chunk * 8] = v;
    }

    const bf16* qp_q = qcat + (long)n * 768 + h * 32 + part * 16;
    bf16x8 qa = *(const bf16x8*)qp_q;
    bf16x8 qb = *(const bf16x8*)(qp_q + 8);
    const bf16* qp_p = qcat + (long)n * 768 + 256 + h * 64 + part * 32;
    bf16x8 p[4];
    p[0] = *(const bf16x8*)qp_p;
    p[1] = *(const bf16x8*)(qp_p + 8);
    p[2] = *(const bf16x8*)(qp_p + 16);
    p[3] = *(const bf16x8*)(qp_p + 24);
    const bf16* kp = localKV + (long)s_s[j] * 512 + h * 32 + part * 16;
    bf16x8 ka = *(const bf16x8*)kp;
    bf16x8 kb = *(const bf16x8*)(kp + 8);

    float sc = 0.f;
    #pragma unroll
    for (int i = 0; i < 8; ++i)
        sc += (float)qa[i] * (float)ka[i] + (float)qb[i] * (float)kb[i];

    const int dbase = part * 32;
    #pragma unroll
    for (int i = 0; i < 4; ++i) {
        const f32x4 a4 = *(const f32x4*)&dist_s[j][dbase + 8 * i];
        const f32x4 b4 = *(const f32x4*)&dist_s[j][dbase + 8 * i + 4];
        sc += a4[0] * (float)p[i][0] + a4[1] * (float)p[i][1]
            + a4[2] * (float)p[i][2] + a4[3] * (float)p[i][3]
            + b4[0] * (float)p[i][4] + b4[1] * (float)p[i][5]
            + b4[2] * (float)p[i][6] + b4[3] * (float)p[i][7];
    }

    sc += __shfl_xor(sc, 1);           // full (pre-scaled) score
    float m = sc;
    m = fmaxf(m, __shfl_xor(m, 2));
    m = fmaxf(m, __shfl_xor(m, 4));
    m = fmaxf(m, __shfl_xor(m, 8));
    m = fmaxf(m, __shfl_xor(m, 16));
    float e = __expf(sc - m);
    float sum = e;
    sum += __shfl_xor(sum, 2);
    sum += __shfl_xor(sum, 4);
    sum += __shfl_xor(sum, 8);
    sum += __shfl_xor(sum, 16);
    float attn = e / sum;
    if (!part) attn_s[h][j] = attn;
    __syncthreads();

    if (t < 128) {
        const int c0 = t * 2;
        const int hh = t >> 4;
        float a0 = 0.f, a1 = 0.f;
        #pragma unroll
        for (int j2 = 0; j2 < 16; ++j2) {
            float wgt = attn_s[hh][j2];
            bf16x2 pv = *(const bf16x2*)&V_s[j2][c0];
            a0 += wgt * (float)pv[0];
            a1 += wgt * (float)pv[1];
        }
        bf16x2 o2; o2[0] = (bf16)a0; o2[1] = (bf16)a1;
        *(bf16x2*)&concat[(long)n * 768 + c0] = o2;
    } else {
        const int u = t - 128;
        const int base = u * 4;
        const int h3 = u >> 4, d3 = (u & 15) * 4;
        f32x4 acc4 = {};
        #pragma unroll
        for (int j2 = 0; j2 < 16; ++j2) {
            float wgt = attn_s[h3][j2];
            const f32x4 dv = *(const f32x4*)&dist_s[j2][d3];
            acc4 += wgt * dv;
        }
        bf16x4 o4;
        #pragma unroll
        for (int i = 0; i < 4; ++i) o4[i] = (bf16)acc4[i];
        *(bf16x4*)&concat[(long)n * 768 + 256 + base] = o4;
    }
}

// ---------------------------------------------------------------------------
extern "C" void kernel_launch(void* const* d_in, const int* in_sizes, int n_in,
                              void* d_out, int out_size, void* d_ws, size_t ws_size,
                              hipStream_t stream)
{
    const float* features = (const float*)d_in[0];
    const float* dist     = (const float*)d_in[1];
    const int*   structure= (const int*)d_in[2];
    const float* W0 = (const float*)d_in[3];
    const float* b0 = (const float*)d_in[4];
    const float* W1 = (const float*)d_in[5];
    const float* b1 = (const float*)d_in[6];
    const float* W2 = (const float*)d_in[7];
    const float* b2 = (const float*)d_in[8];
    const float* Wq = (const float*)d_in[9];
    const float* bq = (const float*)d_in[10];
    const float* Wk = (const float*)d_in[11];
    // d_in[12] = bk : dropped exactly (softmax-invariant per-head shift)
    const float* Wv = (const float*)d_in[13];
    const float* bv = (const float*)d_in[14];
    const float* Wo = (const float*)d_in[15];
    const float* bo = (const float*)d_in[16];
    float* out = (float*)d_out;

    const size_t MB = 1u << 20;
    char* w = (char*)d_ws;
    // live intervals:
    bf16*  fbf     = (bf16*)(w + 0 * MB);    // [0,8)    prep -> g1qcat
    bf16*  local_b = (bf16*)(w + 0 * MB);    // [0,8)    G3 -> KV     (fbf dead)
    bf16*  localKV = (bf16*)(w + 8 * MB);    // [8,24)   KV -> attn
    bf16*  H0      = (bf16*)(w + 16 * MB);   // [16,32)  g1qcat -> G2 (pre-KV)
    bf16*  qcat    = (bf16*)(w + 32 * MB);   // [32,56)  g1qcat -> attn
    bf16*  H1      = (bf16*)(w + 56 * MB);   // [56,72)  G2 -> G3
    bf16*  concat  = (bf16*)(w + 56 * MB);   // [56,80)  attn -> final (H1 dead)
    char*  wb      = w + 80 * MB;            // weights: prep -> final
    bf16*  W0T     = (bf16*)(wb + 0);
    bf16*  W1T     = (bf16*)(wb + 262144);
    bf16*  W2T     = (bf16*)(wb + 786432);
    bf16*  WkvT    = (bf16*)(wb + 1048576);
    bf16*  WqcatT  = (bf16*)(wb + 1310720);
    bf16*  WstackT = (bf16*)(wb + 1703936);
    float* bqcat   = (float*)(wb + 2097152);
    float* biaso   = (float*)(wb + 2100224);

    dim3 blk(256);

    prep_all<<<dim3(5890), blk, 0, stream>>>(
        features, W0, W1, W2, Wq, bq, Wk, Wv, Wo, bo, bv,
        fbf, W0T, W1T, W2T, WkvT, WqcatT, WstackT, bqcat, biaso);

    // fused: H0 = relu(relu(f)@W0+b0) [relu-in-frag]; qcat = f@Wqcat+bqcat
    g1qcat_kernel<<<dim3(10, 128), blk, 0, stream>>>(
        fbf, W0T, b0, WqcatT, bqcat, H0, qcat);

    // W1: H1 = relu(H0@W1+b1)          (BK=64: 512 blocks, 2/CU)
    gemm128<true,  true,  false, bf16, 2><<<dim3(4, 128), blk, 0, stream>>>(
        H0, W1T, b1, nullptr, H1, NN, 512, 512);
    // W2: local = relu(H1@W2+b2)       (256 blocks)
    gemm128<true,  true,  false, bf16, 2><<<dim3(2, 128), blk, 0, stream>>>(
        H1, W2T, b2, nullptr, local_b, NN, 256, 512);
    // KV: localKV = local @ [Wk|Wv]    (512 blocks)
    gemm128<false, false, false, bf16, 2><<<dim3(4, 128), blk, 0, stream>>>(
        local_b, WkvT, nullptr, nullptr, localKV, NN, 512, 256);

    attn_kernel<<<dim3(NN), blk, 0, stream>>>(
        qcat, localKV, dist, structure, concat);

    // out = concat @ [Wo ; U] + (bo + bv@Wo) + features  (256 blocks)
    gemm128<true,  false, true,  float, 2><<<dim3(2, 128), blk, 0, stream>>>(
        concat, WstackT, biaso, features, out, NN, 256, 768);
}

// Round 15
// 157.064 us; speedup vs baseline: 1.0221x; 1.0061x over previous
//
#include <hip/hip_runtime.h>
#include <hip/hip_bf16.h>

#define NN 16384
#define SIZE 256
#define DISTD 64
#define KNBR 16
#define HEADS 8
#define HIDDEN 512
#define HA 256
#define SCALE 0.17677669529663687f

typedef __bf16 bf16;
typedef bf16 bf16x2 __attribute__((ext_vector_type(2)));
typedef bf16 bf16x4 __attribute__((ext_vector_type(4)));
typedef bf16 bf16x8 __attribute__((ext_vector_type(8)));
typedef float f32x4 __attribute__((ext_vector_type(4)));

__device__ __forceinline__ void gload16(const void* g, void* l) {
    __builtin_amdgcn_global_load_lds(
        (const __attribute__((address_space(1))) unsigned int*)g,
        (__attribute__((address_space(3))) unsigned int*)l, 16, 0, 0);
}

// packed bf16 relu on a dword (2 lanes): negative lanes -> 0x0000.
__device__ __forceinline__ unsigned int relu2bf(unsigned int x) {
    unsigned int s = x & 0x80008000u;
    unsigned int mask = (s - (s >> 15)) | s;   // 0xFFFF in negative lanes
    return x & ~mask;
}

// ---------------------------------------------------------------------------
// 2-phase double-buffered 128x128 GEMM, BK = 32*SUBS (SUBS=2 proven r8).
// ---------------------------------------------------------------------------
template<bool BIAS, bool RELU_OUT, bool RESID, typename OutT, int SUBS>
__global__ __launch_bounds__(256) void gemm128(
    const bf16* __restrict__ A, const bf16* __restrict__ BT,
    const float* __restrict__ bias, const float* __restrict__ resid,
    OutT* __restrict__ C, int M, int N, int K)
{
    __shared__ alignas(16) bf16 As[2][SUBS][128][32];
    __shared__ alignas(16) bf16 Bs[2][SUBS][128][32];

    const int t = threadIdx.x;
    const int w = t >> 6, l = t & 63;
    const int bm = blockIdx.y * 128, bn = blockIdx.x * 128;
    const int wr = (w >> 1) * 64, wc = (w & 1) * 64;
    const int BK = 32 * SUBS;

    f32x4 acc[4][4] = {};

    const bf16* ag = A  + (size_t)(bm + (t >> 2)) * K + (t & 3) * 8;
    const bf16* bg = BT + (size_t)(bn + (t >> 2)) * K + (t & 3) * 8;

    auto STAGE = [&](int buf, int k0) {
        #pragma unroll
        for (int s = 0; s < SUBS; ++s) {
            bf16* asl = &As[buf][s][w << 4][0];
            bf16* bsl = &Bs[buf][s][w << 4][0];
            gload16(ag + k0 + s * 32, asl);
            gload16(ag + k0 + s * 32 + (size_t)64 * K, (char*)asl + 4096);
            gload16(bg + k0 + s * 32, bsl);
            gload16(bg + k0 + s * 32 + (size_t)64 * K, (char*)bsl + 4096);
        }
    };

    const int nt = K / BK;
    STAGE(0, 0);
    __syncthreads();

    for (int tt = 0; tt < nt; ++tt) {
        const int cur = tt & 1;
        if (tt + 1 < nt) STAGE(cur ^ 1, (tt + 1) * BK);

        #pragma unroll
        for (int s = 0; s < SUBS; ++s) {
            bf16x8 af[4], bfr[4];
            #pragma unroll
            for (int m = 0; m < 4; ++m)
                af[m] = *(const bf16x8*)&As[cur][s][wr + m * 16 + (l & 15)][(l >> 4) * 8];
            #pragma unroll
            for (int n2 = 0; n2 < 4; ++n2)
                bfr[n2] = *(const bf16x8*)&Bs[cur][s][wc + n2 * 16 + (l & 15)][(l >> 4) * 8];
            #pragma unroll
            for (int m = 0; m < 4; ++m)
                #pragma unroll
                for (int n2 = 0; n2 < 4; ++n2)
                    acc[m][n2] = __builtin_amdgcn_mfma_f32_16x16x32_bf16(
                        af[m], bfr[n2], acc[m][n2], 0, 0, 0);
        }
        __syncthreads();
    }

    #pragma unroll
    for (int m = 0; m < 4; ++m) {
        const int row = bm + wr + m * 16 + ((l >> 4) << 2);
        #pragma unroll
        for (int n2 = 0; n2 < 4; ++n2) {
            const int col = bn + wc + n2 * 16 + (l & 15);
            #pragma unroll
            for (int i = 0; i < 4; ++i) {
                float v = acc[m][n2][i];
                if (BIAS) v += bias[col];
                if (RESID) v += resid[(size_t)(row + i) * N + col];
                if (RELU_OUT) v = fmaxf(v, 0.f);
                C[(size_t)(row + i) * N + col] = (OutT)v;
            }
        }
    }
}

// ---------------------------------------------------------------------------
// Fused G1 + qcat dispatch (both K=256), BK=32. grid (10,128):
//  bx<4 : H0   = relu(relu(f) @ W0T + b0)   — relu on A applied IN-FRAGMENT
//  bx>=4: qcat = f @ Wqcat_cols + bqcat      (bf16, ld 768, pre-scaled)
// ---------------------------------------------------------------------------
__global__ __launch_bounds__(256) void g1qcat_kernel(
    const bf16* __restrict__ fbf,
    const bf16* __restrict__ W0T, const float* __restrict__ b0,
    const bf16* __restrict__ WqcatT, const float* __restrict__ bqcat,
    bf16* __restrict__ H0, bf16* __restrict__ qcat)
{
    __shared__ alignas(16) bf16 As[2][128][32];
    __shared__ alignas(16) bf16 Bs[2][128][32];

    const int bx = blockIdx.x, by = blockIdx.y;
    const bool isG1 = bx < 4;
    const int cx = bx - 4;
    const bf16* BT = isG1 ? (W0T + (size_t)bx * 128 * 256)
                          : (WqcatT + (size_t)cx * 128 * 256);
    const float* bias = isG1 ? (b0 + bx * 128) : (bqcat + cx * 128);
    const int K = 256;

    const int t = threadIdx.x;
    const int w = t >> 6, l = t & 63;
    const int bm = by * 128;
    const int wr = (w >> 1) * 64, wc = (w & 1) * 64;

    f32x4 acc[4][4] = {};

    const bf16* ag = fbf + (size_t)(bm + (t >> 2)) * K + (t & 3) * 8;
    const bf16* bg = BT  + (size_t)(t >> 2) * K + (t & 3) * 8;

    {
        bf16* asl = &As[0][w << 4][0];
        bf16* bsl = &Bs[0][w << 4][0];
        gload16(ag, asl);
        gload16(ag + (size_t)64 * K, (char*)asl + 4096);
        gload16(bg, bsl);
        gload16(bg + (size_t)64 * K, (char*)bsl + 4096);
    }
    __syncthreads();

    for (int tt = 0; tt < 8; ++tt) {
        const int cur = tt & 1;
        if (tt + 1 < 8) {
            const int k0 = (tt + 1) << 5;
            bf16* asl = &As[cur ^ 1][w << 4][0];
            bf16* bsl = &Bs[cur ^ 1][w << 4][0];
            gload16(ag + k0, asl);
            gload16(ag + k0 + (size_t)64 * K, (char*)asl + 4096);
            gload16(bg + k0, bsl);
            gload16(bg + k0 + (size_t)64 * K, (char*)bsl + 4096);
        }
        bf16x8 af[4], bfr[4];
        #pragma unroll
        for (int m = 0; m < 4; ++m)
            af[m] = *(const bf16x8*)&As[cur][wr + m * 16 + (l & 15)][(l >> 4) * 8];
        if (isG1) {     // uniform branch: relu(A) in-register (exact vs frbf)
            #pragma unroll
            for (int m = 0; m < 4; ++m) {
                unsigned int* u = (unsigned int*)&af[m];
                #pragma unroll
                for (int q2 = 0; q2 < 4; ++q2) u[q2] = relu2bf(u[q2]);
            }
        }
        #pragma unroll
        for (int n2 = 0; n2 < 4; ++n2)
            bfr[n2] = *(const bf16x8*)&Bs[cur][wc + n2 * 16 + (l & 15)][(l >> 4) * 8];
        #pragma unroll
        for (int m = 0; m < 4; ++m)
            #pragma unroll
            for (int n2 = 0; n2 < 4; ++n2)
                acc[m][n2] = __builtin_amdgcn_mfma_f32_16x16x32_bf16(
                    af[m], bfr[n2], acc[m][n2], 0, 0, 0);
        __syncthreads();
    }

    #pragma unroll
    for (int m = 0; m < 4; ++m) {
        const int lrow = wr + m * 16 + ((l >> 4) << 2);
        #pragma unroll
        for (int n2 = 0; n2 < 4; ++n2) {
            const int lcol = wc + n2 * 16 + (l & 15);
            #pragma unroll
            for (int i = 0; i < 4; ++i) {
                float v = acc[m][n2][i] + bias[lcol];
                const size_t row = bm + lrow + i;
                if (isG1) {
                    H0[row * 512 + bx * 128 + lcol] = (bf16)fmaxf(v, 0.f);
                } else {
                    qcat[row * 768 + cx * 128 + lcol] = (bf16)v;
                }
            }
        }
    }
}

// ---------------------------------------------------------------------------
// Fused prep with COALESCED LDS-tiled transposes (r10-proven); frbf dropped.
// ---------------------------------------------------------------------------
__global__ __launch_bounds__(256) void prep_all(
    const float* __restrict__ features,
    const float* __restrict__ W0, const float* __restrict__ W1,
    const float* __restrict__ W2, const float* __restrict__ Wq,
    const float* __restrict__ bq, const float* __restrict__ Wk,
    const float* __restrict__ Wv, const float* __restrict__ Wo,
    const float* __restrict__ bo, const float* __restrict__ bv,
    bf16* __restrict__ fbf,
    bf16* __restrict__ W0T, bf16* __restrict__ W1T, bf16* __restrict__ W2T,
    bf16* __restrict__ WkvT, bf16* __restrict__ WqcatT, bf16* __restrict__ WstackT,
    float* __restrict__ bqcat, float* __restrict__ biaso)
{
    __shared__ float tl[32][33];
    const int t = threadIdx.x;

    if (blockIdx.x < 4096) {
        int id = blockIdx.x * 256 + t;
        float4 v = ((const float4*)features)[id];
        bf16x4 a;
        a[0] = (bf16)v.x; a[1] = (bf16)v.y; a[2] = (bf16)v.z; a[3] = (bf16)v.w;
        ((bf16x4*)fbf)[id] = a;
        return;
    }
    if (blockIdx.x < 4864) {
        int tile = blockIdx.x - 4096;
        const float* src; bf16* dst; int srcLd, dstLd, tpr; float scl = 1.f;
        if (tile < 128)      { src = W0; srcLd = 512; tpr = 16; dst = W0T;  dstLd = 256; }
        else if (tile < 384) { tile -= 128; src = W1; srcLd = 512; tpr = 16; dst = W1T;  dstLd = 512; }
        else if (tile < 512) { tile -= 384; src = W2; srcLd = 256; tpr = 8;  dst = W2T;  dstLd = 512; }
        else if (tile < 576) { tile -= 512; src = Wk; srcLd = 256; tpr = 8;  dst = WkvT; dstLd = 256; }
        else if (tile < 640) { tile -= 576; src = Wv; srcLd = 256; tpr = 8;  dst = WkvT + 65536; dstLd = 256; }
        else if (tile < 704) { tile -= 640; src = Wq; srcLd = 256; tpr = 8;  dst = WqcatT; dstLd = 256; scl = SCALE; }
        else                 { tile -= 704; src = Wo; srcLd = 256; tpr = 8;  dst = WstackT; dstLd = 768; }
        const int tr = tile / tpr, tc = tile % tpr;
        const int x = t & 31, y0 = t >> 5;
        #pragma unroll
        for (int p = 0; p < 4; ++p) {
            int y = y0 + 8 * p;
            tl[y][x] = src[(size_t)(tr * 32 + y) * srcLd + tc * 32 + x];
        }
        __syncthreads();
        #pragma unroll
        for (int p = 0; p < 4; ++p) {
            int a2 = y0 + 8 * p;
            dst[(size_t)(tc * 32 + a2) * dstLd + tr * 32 + x] = (bf16)(tl[x][a2] * scl);
        }
        return;
    }
    if (blockIdx.x < 5376) {
        int id = (blockIdx.x - 4864) * 256 + t;
        int hd = id >> 8, c = id & 255;
        int h = hd >> 6, d = hd & 63;
        float s = 0.f;
        #pragma unroll
        for (int a = 0; a < 32; ++a)
            s += Wq[(size_t)c * 256 + h * 32 + a] * Wk[(size_t)(256 + d) * 256 + h * 32 + a];
        WqcatT[65536 + id] = (bf16)(s * SCALE);
        return;
    }
    if (blockIdx.x < 5888) {
        int id = (blockIdx.x - 5376) * 256 + t;
        int r2 = id >> 8, col = id & 255;
        int h = r2 >> 6, d = r2 & 63;
        float s = 0.f;
        #pragma unroll
        for (int a = 0; a < 32; ++a)
            s += Wv[(size_t)(256 + d) * 256 + h * 32 + a] * Wo[(size_t)(h * 32 + a) * 256 + col];
        WstackT[(size_t)col * 768 + 256 + r2] = (bf16)s;
        return;
    }
    if (blockIdx.x == 5888) {
        #pragma unroll
        for (int rep = 0; rep < 3; ++rep) {
            int idx = rep * 256 + t;
            if (idx >= 768) break;
            float s;
            if (idx < 256) s = bq[idx];
            else {
                int hd = idx - 256, h = hd >> 6, d = hd & 63;
                s = 0.f;
                #pragma unroll
                for (int a = 0; a < 32; ++a)
                    s += bq[h * 32 + a] * Wk[(size_t)(256 + d) * 256 + h * 32 + a];
            }
            bqcat[idx] = s * SCALE;
        }
        return;
    }
    {   // biaso = bo + bv @ Wo
        float s = bo[t];
        for (int u = 0; u < 256; ++u) s += bv[u] * Wo[(size_t)u * 256 + t];
        biaso[t] = s;
    }
}

// ---------------------------------------------------------------------------
// Attention: r12/r14 structure + (1) v_dot2_f32_bf16 for the K-score part
// (guarded; fallback = proven path) and (2) dist staged via one float4 load
// + one ds_write_b128 per thread (was 4 scalar loads + 4 scalar stores).
// ---------------------------------------------------------------------------
__global__ __launch_bounds__(256) void attn_kernel(
    const bf16* __restrict__ qcat,      // [NN, 768]  (q | qproj), pre-scaled
    const bf16* __restrict__ localKV,   // [NN, 512]  (K | V)
    const float* __restrict__ dist,     // [NN, 16, 64]
    const int*  __restrict__ structure, // [NN, 16]
    bf16* __restrict__ concat)          // [NN, 768]
{
    const int n = blockIdx.x;
    const int t = threadIdx.x;
    const int h = t >> 5, j = (t >> 1) & 15, part = t & 1;

    __shared__ float dist_s[16][68];   // 272B rows: 16B-aligned for b128 ops
    __shared__ bf16  V_s[16][264];
    __shared__ float attn_s[8][16];
    __shared__ int   s_s[16];

    {   // dist staging: thread t covers floats [4t, 4t+4)  (coalesced 16B)
        const float* dp = dist + (size_t)n * (KNBR * DISTD);
        float4 dv4 = ((const float4*)dp)[t];
        f32x4 w4; w4[0] = dv4.x; w4[1] = dv4.y; w4[2] = dv4.z; w4[3] = dv4.w;
        *(f32x4*)&dist_s[t >> 4][(t & 15) * 4] = w4;
    }
    if (t < 16) s_s[t] = structure[(size_t)n * KNBR + t];
    __syncthreads();

    #pragma unroll
    for (int pass = 0; pass < 2; ++pass) {
        int idx = pass * 256 + t;
        int row = idx >> 5, chunk = idx & 31;
        bf16x8 v = *(const bf16x8*)(localKV + (size_t)s_s[row] * 512 + 256 + chunk * 8);
        *(bf16x8*)&V_s[row][chunk * 8] = v;
    }

    const bf16* qp_q = qcat + (size_t)n * 768 + h * 32 + part * 16;
    bf16x8 qa = *(const bf16x8*)qp_q;
    bf16x8 qb = *(const bf16x8*)(qp_q + 8);
    const bf16* qp_p = qcat + (size_t)n * 768 + 256 + h * 64 + part * 32;
    bf16x8 p[4];
    p[0] = *(const bf16x8*)qp_p;
    p[1] = *(const bf16x8*)(qp_p + 8);
    p[2] = *(const bf16x8*)(qp_p + 16);
    p[3] = *(const bf16x8*)(qp_p + 24);
    const bf16* kp = localKV + (size_t)s_s[j] * 512 + h * 32 + part * 16;
    bf16x8 ka = *(const bf16x8*)kp;
    bf16x8 kb = *(const bf16x8*)(kp + 8);

    float sc = 0.f;
#if __has_builtin(__builtin_amdgcn_fdot2_f32_bf16)
    {
        const bf16x2* qa2 = (const bf16x2*)&qa;
        const bf16x2* qb2 = (const bf16x2*)&qb;
        const bf16x2* ka2 = (const bf16x2*)&ka;
        const bf16x2* kb2 = (const bf16x2*)&kb;
        #pragma unroll
        for (int i = 0; i < 4; ++i)
            sc = __builtin_amdgcn_fdot2_f32_bf16(qa2[i], ka2[i], sc, false);
        #pragma unroll
        for (int i = 0; i < 4; ++i)
            sc = __builtin_amdgcn_fdot2_f32_bf16(qb2[i], kb2[i], sc, false);
    }
#else
    #pragma unroll
    for (int i = 0; i < 8; ++i)
        sc += (float)qa[i] * (float)ka[i] + (float)qb[i] * (float)kb[i];
#endif

    const int dbase = part * 32;
    #pragma unroll
    for (int i = 0; i < 4; ++i) {
        const f32x4 a4 = *(const f32x4*)&dist_s[j][dbase + 8 * i];
        const f32x4 b4 = *(const f32x4*)&dist_s[j][dbase + 8 * i + 4];
        sc += a4[0] * (float)p[i][0] + a4[1] * (float)p[i][1]
            + a4[2] * (float)p[i][2] + a4[3] * (float)p[i][3]
            + b4[0] * (float)p[i][4] + b4[1] * (float)p[i][5]
            + b4[2] * (float)p[i][6] + b4[3] * (float)p[i][7];
    }

    sc += __shfl_xor(sc, 1);           // full (pre-scaled) score
    float m = sc;
    m = fmaxf(m, __shfl_xor(m, 2));
    m = fmaxf(m, __shfl_xor(m, 4));
    m = fmaxf(m, __shfl_xor(m, 8));
    m = fmaxf(m, __shfl_xor(m, 16));
    float e = __expf(sc - m);
    float sum = e;
    sum += __shfl_xor(sum, 2);
    sum += __shfl_xor(sum, 4);
    sum += __shfl_xor(sum, 8);
    sum += __shfl_xor(sum, 16);
    float attn = e / sum;
    if (!part) attn_s[h][j] = attn;
    __syncthreads();

    if (t < 128) {
        const int c0 = t * 2;
        const int hh = t >> 4;
        float a0 = 0.f, a1 = 0.f;
        #pragma unroll
        for (int j2 = 0; j2 < 16; ++j2) {
            float wgt = attn_s[hh][j2];
            bf16x2 pv = *(const bf16x2*)&V_s[j2][c0];
            a0 += wgt * (float)pv[0];
            a1 += wgt * (float)pv[1];
        }
        bf16x2 o2; o2[0] = (bf16)a0; o2[1] = (bf16)a1;
        *(bf16x2*)&concat[(size_t)n * 768 + c0] = o2;
    } else {
        const int u = t - 128;
        const int base = u * 4;
        const int h3 = u >> 4, d3 = (u & 15) * 4;
        f32x4 acc4 = {};
        #pragma unroll
        for (int j2 = 0; j2 < 16; ++j2) {
            float wgt = attn_s[h3][j2];
            const f32x4 dv = *(const f32x4*)&dist_s[j2][d3];
            acc4 += wgt * dv;
        }
        bf16x4 o4;
        #pragma unroll
        for (int i = 0; i < 4; ++i) o4[i] = (bf16)acc4[i];
        *(bf16x4*)&concat[(size_t)n * 768 + 256 + base] = o4;
    }
}

// ---------------------------------------------------------------------------
extern "C" void kernel_launch(void* const* d_in, const int* in_sizes, int n_in,
                              void* d_out, int out_size, void* d_ws, size_t ws_size,
                              hipStream_t stream)
{
    const float* features = (const float*)d_in[0];
    const float* dist     = (const float*)d_in[1];
    const int*   structure= (const int*)d_in[2];
    const float* W0 = (const float*)d_in[3];
    const float* b0 = (const float*)d_in[4];
    const float* W1 = (const float*)d_in[5];
    const float* b1 = (const float*)d_in[6];
    const float* W2 = (const float*)d_in[7];
    const float* b2 = (const float*)d_in[8];
    const float* Wq = (const float*)d_in[9];
    const float* bq = (const float*)d_in[10];
    const float* Wk = (const float*)d_in[11];
    // d_in[12] = bk : dropped exactly (softmax-invariant per-head shift)
    const float* Wv = (const float*)d_in[13];
    const float* bv = (const float*)d_in[14];
    const float* Wo = (const float*)d_in[15];
    const float* bo = (const float*)d_in[16];
    float* out = (float*)d_out;

    const size_t MB = 1u << 20;
    char* w = (char*)d_ws;
    // live intervals:
    bf16*  fbf     = (bf16*)(w + 0 * MB);    // [0,8)    prep -> g1qcat
    bf16*  local_b = (bf16*)(w + 0 * MB);    // [0,8)    G3 -> KV     (fbf dead)
    bf16*  localKV = (bf16*)(w + 8 * MB);    // [8,24)   KV -> attn
    bf16*  H0      = (bf16*)(w + 16 * MB);   // [16,32)  g1qcat -> G2 (pre-KV)
    bf16*  qcat    = (bf16*)(w + 32 * MB);   // [32,56)  g1qcat -> attn
    bf16*  H1      = (bf16*)(w + 56 * MB);   // [56,72)  G2 -> G3
    bf16*  concat  = (bf16*)(w + 56 * MB);   // [56,80)  attn -> final (H1 dead)
    char*  wb      = w + 80 * MB;            // weights: prep -> final
    bf16*  W0T     = (bf16*)(wb + 0);
    bf16*  W1T     = (bf16*)(wb + 262144);
    bf16*  W2T     = (bf16*)(wb + 786432);
    bf16*  WkvT    = (bf16*)(wb + 1048576);
    bf16*  WqcatT  = (bf16*)(wb + 1310720);
    bf16*  WstackT = (bf16*)(wb + 1703936);
    float* bqcat   = (float*)(wb + 2097152);
    float* biaso   = (float*)(wb + 2100224);

    dim3 blk(256);

    prep_all<<<dim3(5890), blk, 0, stream>>>(
        features, W0, W1, W2, Wq, bq, Wk, Wv, Wo, bo, bv,
        fbf, W0T, W1T, W2T, WkvT, WqcatT, WstackT, bqcat, biaso);

    // fused: H0 = relu(relu(f)@W0+b0) [relu-in-frag]; qcat = f@Wqcat+bqcat
    g1qcat_kernel<<<dim3(10, 128), blk, 0, stream>>>(
        fbf, W0T, b0, WqcatT, bqcat, H0, qcat);

    // W1: H1 = relu(H0@W1+b1)          (BK=64: 512 blocks, 2/CU)
    gemm128<true,  true,  false, bf16, 2><<<dim3(4, 128), blk, 0, stream>>>(
        H0, W1T, b1, nullptr, H1, NN, 512, 512);
    // W2: local = relu(H1@W2+b2)       (256 blocks)
    gemm128<true,  true,  false, bf16, 2><<<dim3(2, 128), blk, 0, stream>>>(
        H1, W2T, b2, nullptr, local_b, NN, 256, 512);
    // KV: localKV = local @ [Wk|Wv]    (512 blocks)
    gemm128<false, false, false, bf16, 2><<<dim3(4, 128), blk, 0, stream>>>(
        local_b, WkvT, nullptr, nullptr, localKV, NN, 512, 256);

    attn_kernel<<<dim3(NN), blk, 0, stream>>>(
        qcat, localKV, dist, structure, concat);

    // out = concat @ [Wo ; U] + (bo + bv@Wo) + features  (256 blocks)
    gemm128<true,  false, true,  float, 2><<<dim3(2, 128), blk, 0, stream>>>(
        concat, WstackT, biaso, features, out, NN, 256, 768);
}

// Round 16
// 156.701 us; speedup vs baseline: 1.0245x; 1.0023x over previous
//
#include <hip/hip_runtime.h>
#include <hip/hip_bf16.h>

#define NN 16384
#define SIZE 256
#define DISTD 64
#define KNBR 16
#define HEADS 8
#define HIDDEN 512
#define HA 256
#define SCALE 0.17677669529663687f

typedef __bf16 bf16;
typedef bf16 bf16x2 __attribute__((ext_vector_type(2)));
typedef bf16 bf16x4 __attribute__((ext_vector_type(4)));
typedef bf16 bf16x8 __attribute__((ext_vector_type(8)));
typedef float f32x4 __attribute__((ext_vector_type(4)));

__device__ __forceinline__ void gload16(const void* g, void* l) {
    __builtin_amdgcn_global_load_lds(
        (const __attribute__((address_space(1))) unsigned int*)g,
        (__attribute__((address_space(3))) unsigned int*)l, 16, 0, 0);
}

// packed bf16 relu on a dword (2 lanes): negative lanes -> 0x0000.
__device__ __forceinline__ unsigned int relu2bf(unsigned int x) {
    unsigned int s = x & 0x80008000u;
    unsigned int mask = (s - (s >> 15)) | s;   // 0xFFFF in negative lanes
    return x & ~mask;
}

// ---------------------------------------------------------------------------
// 2-phase double-buffered 128x128 GEMM, BK = 32*SUBS (SUBS=2 proven r8).
// ---------------------------------------------------------------------------
template<bool BIAS, bool RELU_OUT, bool RESID, typename OutT, int SUBS>
__global__ __launch_bounds__(256) void gemm128(
    const bf16* __restrict__ A, const bf16* __restrict__ BT,
    const float* __restrict__ bias, const float* __restrict__ resid,
    OutT* __restrict__ C, int M, int N, int K)
{
    __shared__ alignas(16) bf16 As[2][SUBS][128][32];
    __shared__ alignas(16) bf16 Bs[2][SUBS][128][32];

    const int t = threadIdx.x;
    const int w = t >> 6, l = t & 63;
    const int bm = blockIdx.y * 128, bn = blockIdx.x * 128;
    const int wr = (w >> 1) * 64, wc = (w & 1) * 64;
    const int BK = 32 * SUBS;

    f32x4 acc[4][4] = {};

    const bf16* ag = A  + (size_t)(bm + (t >> 2)) * K + (t & 3) * 8;
    const bf16* bg = BT + (size_t)(bn + (t >> 2)) * K + (t & 3) * 8;

    auto STAGE = [&](int buf, int k0) {
        #pragma unroll
        for (int s = 0; s < SUBS; ++s) {
            bf16* asl = &As[buf][s][w << 4][0];
            bf16* bsl = &Bs[buf][s][w << 4][0];
            gload16(ag + k0 + s * 32, asl);
            gload16(ag + k0 + s * 32 + (size_t)64 * K, (char*)asl + 4096);
            gload16(bg + k0 + s * 32, bsl);
            gload16(bg + k0 + s * 32 + (size_t)64 * K, (char*)bsl + 4096);
        }
    };

    const int nt = K / BK;
    STAGE(0, 0);
    __syncthreads();

    for (int tt = 0; tt < nt; ++tt) {
        const int cur = tt & 1;
        if (tt + 1 < nt) STAGE(cur ^ 1, (tt + 1) * BK);

        #pragma unroll
        for (int s = 0; s < SUBS; ++s) {
            bf16x8 af[4], bfr[4];
            #pragma unroll
            for (int m = 0; m < 4; ++m)
                af[m] = *(const bf16x8*)&As[cur][s][wr + m * 16 + (l & 15)][(l >> 4) * 8];
            #pragma unroll
            for (int n2 = 0; n2 < 4; ++n2)
                bfr[n2] = *(const bf16x8*)&Bs[cur][s][wc + n2 * 16 + (l & 15)][(l >> 4) * 8];
            #pragma unroll
            for (int m = 0; m < 4; ++m)
                #pragma unroll
                for (int n2 = 0; n2 < 4; ++n2)
                    acc[m][n2] = __builtin_amdgcn_mfma_f32_16x16x32_bf16(
                        af[m], bfr[n2], acc[m][n2], 0, 0, 0);
        }
        __syncthreads();
    }

    #pragma unroll
    for (int m = 0; m < 4; ++m) {
        const int row = bm + wr + m * 16 + ((l >> 4) << 2);
        #pragma unroll
        for (int n2 = 0; n2 < 4; ++n2) {
            const int col = bn + wc + n2 * 16 + (l & 15);
            #pragma unroll
            for (int i = 0; i < 4; ++i) {
                float v = acc[m][n2][i];
                if (BIAS) v += bias[col];
                if (RESID) v += resid[(size_t)(row + i) * N + col];
                if (RELU_OUT) v = fmaxf(v, 0.f);
                C[(size_t)(row + i) * N + col] = (OutT)v;
            }
        }
    }
}

// ---------------------------------------------------------------------------
// Fused G1 + qcat dispatch (both K=256), BK=32. grid (10,128):
//  bx<4 : H0   = relu(relu(f) @ W0T + b0)   — relu on A applied IN-FRAGMENT
//  bx>=4: qcat = f @ Wqcat_cols + bqcat      (bf16, ld 768, pre-scaled)
// ---------------------------------------------------------------------------
__global__ __launch_bounds__(256) void g1qcat_kernel(
    const bf16* __restrict__ fbf,
    const bf16* __restrict__ W0T, const float* __restrict__ b0,
    const bf16* __restrict__ WqcatT, const float* __restrict__ bqcat,
    bf16* __restrict__ H0, bf16* __restrict__ qcat)
{
    __shared__ alignas(16) bf16 As[2][128][32];
    __shared__ alignas(16) bf16 Bs[2][128][32];

    const int bx = blockIdx.x, by = blockIdx.y;
    const bool isG1 = bx < 4;
    const int cx = bx - 4;
    const bf16* BT = isG1 ? (W0T + (size_t)bx * 128 * 256)
                          : (WqcatT + (size_t)cx * 128 * 256);
    const float* bias = isG1 ? (b0 + bx * 128) : (bqcat + cx * 128);
    const int K = 256;

    const int t = threadIdx.x;
    const int w = t >> 6, l = t & 63;
    const int bm = by * 128;
    const int wr = (w >> 1) * 64, wc = (w & 1) * 64;

    f32x4 acc[4][4] = {};

    const bf16* ag = fbf + (size_t)(bm + (t >> 2)) * K + (t & 3) * 8;
    const bf16* bg = BT  + (size_t)(t >> 2) * K + (t & 3) * 8;

    {
        bf16* asl = &As[0][w << 4][0];
        bf16* bsl = &Bs[0][w << 4][0];
        gload16(ag, asl);
        gload16(ag + (size_t)64 * K, (char*)asl + 4096);
        gload16(bg, bsl);
        gload16(bg + (size_t)64 * K, (char*)bsl + 4096);
    }
    __syncthreads();

    for (int tt = 0; tt < 8; ++tt) {
        const int cur = tt & 1;
        if (tt + 1 < 8) {
            const int k0 = (tt + 1) << 5;
            bf16* asl = &As[cur ^ 1][w << 4][0];
            bf16* bsl = &Bs[cur ^ 1][w << 4][0];
            gload16(ag + k0, asl);
            gload16(ag + k0 + (size_t)64 * K, (char*)asl + 4096);
            gload16(bg + k0, bsl);
            gload16(bg + k0 + (size_t)64 * K, (char*)bsl + 4096);
        }
        bf16x8 af[4], bfr[4];
        #pragma unroll
        for (int m = 0; m < 4; ++m)
            af[m] = *(const bf16x8*)&As[cur][wr + m * 16 + (l & 15)][(l >> 4) * 8];
        if (isG1) {     // uniform branch: relu(A) in-register (exact vs frbf)
            #pragma unroll
            for (int m = 0; m < 4; ++m) {
                unsigned int* u = (unsigned int*)&af[m];
                #pragma unroll
                for (int q2 = 0; q2 < 4; ++q2) u[q2] = relu2bf(u[q2]);
            }
        }
        #pragma unroll
        for (int n2 = 0; n2 < 4; ++n2)
            bfr[n2] = *(const bf16x8*)&Bs[cur][wc + n2 * 16 + (l & 15)][(l >> 4) * 8];
        #pragma unroll
        for (int m = 0; m < 4; ++m)
            #pragma unroll
            for (int n2 = 0; n2 < 4; ++n2)
                acc[m][n2] = __builtin_amdgcn_mfma_f32_16x16x32_bf16(
                    af[m], bfr[n2], acc[m][n2], 0, 0, 0);
        __syncthreads();
    }

    #pragma unroll
    for (int m = 0; m < 4; ++m) {
        const int lrow = wr + m * 16 + ((l >> 4) << 2);
        #pragma unroll
        for (int n2 = 0; n2 < 4; ++n2) {
            const int lcol = wc + n2 * 16 + (l & 15);
            #pragma unroll
            for (int i = 0; i < 4; ++i) {
                float v = acc[m][n2][i] + bias[lcol];
                const size_t row = bm + lrow + i;
                if (isG1) {
                    H0[row * 512 + bx * 128 + lcol] = (bf16)fmaxf(v, 0.f);
                } else {
                    qcat[row * 768 + cx * 128 + lcol] = (bf16)v;
                }
            }
        }
    }
}

// ---------------------------------------------------------------------------
// Fused prep with COALESCED LDS-tiled transposes (r10-proven); frbf dropped.
// ---------------------------------------------------------------------------
__global__ __launch_bounds__(256) void prep_all(
    const float* __restrict__ features,
    const float* __restrict__ W0, const float* __restrict__ W1,
    const float* __restrict__ W2, const float* __restrict__ Wq,
    const float* __restrict__ bq, const float* __restrict__ Wk,
    const float* __restrict__ Wv, const float* __restrict__ Wo,
    const float* __restrict__ bo, const float* __restrict__ bv,
    bf16* __restrict__ fbf,
    bf16* __restrict__ W0T, bf16* __restrict__ W1T, bf16* __restrict__ W2T,
    bf16* __restrict__ WkvT, bf16* __restrict__ WqcatT, bf16* __restrict__ WstackT,
    float* __restrict__ bqcat, float* __restrict__ biaso)
{
    __shared__ float tl[32][33];
    const int t = threadIdx.x;

    if (blockIdx.x < 4096) {
        int id = blockIdx.x * 256 + t;
        float4 v = ((const float4*)features)[id];
        bf16x4 a;
        a[0] = (bf16)v.x; a[1] = (bf16)v.y; a[2] = (bf16)v.z; a[3] = (bf16)v.w;
        ((bf16x4*)fbf)[id] = a;
        return;
    }
    if (blockIdx.x < 4864) {
        int tile = blockIdx.x - 4096;
        const float* src; bf16* dst; int srcLd, dstLd, tpr; float scl = 1.f;
        if (tile < 128)      { src = W0; srcLd = 512; tpr = 16; dst = W0T;  dstLd = 256; }
        else if (tile < 384) { tile -= 128; src = W1; srcLd = 512; tpr = 16; dst = W1T;  dstLd = 512; }
        else if (tile < 512) { tile -= 384; src = W2; srcLd = 256; tpr = 8;  dst = W2T;  dstLd = 512; }
        else if (tile < 576) { tile -= 512; src = Wk; srcLd = 256; tpr = 8;  dst = WkvT; dstLd = 256; }
        else if (tile < 640) { tile -= 576; src = Wv; srcLd = 256; tpr = 8;  dst = WkvT + 65536; dstLd = 256; }
        else if (tile < 704) { tile -= 640; src = Wq; srcLd = 256; tpr = 8;  dst = WqcatT; dstLd = 256; scl = SCALE; }
        else                 { tile -= 704; src = Wo; srcLd = 256; tpr = 8;  dst = WstackT; dstLd = 768; }
        const int tr = tile / tpr, tc = tile % tpr;
        const int x = t & 31, y0 = t >> 5;
        #pragma unroll
        for (int p = 0; p < 4; ++p) {
            int y = y0 + 8 * p;
            tl[y][x] = src[(size_t)(tr * 32 + y) * srcLd + tc * 32 + x];
        }
        __syncthreads();
        #pragma unroll
        for (int p = 0; p < 4; ++p) {
            int a2 = y0 + 8 * p;
            dst[(size_t)(tc * 32 + a2) * dstLd + tr * 32 + x] = (bf16)(tl[x][a2] * scl);
        }
        return;
    }
    if (blockIdx.x < 5376) {
        int id = (blockIdx.x - 4864) * 256 + t;
        int hd = id >> 8, c = id & 255;
        int h = hd >> 6, d = hd & 63;
        float s = 0.f;
        #pragma unroll
        for (int a = 0; a < 32; ++a)
            s += Wq[(size_t)c * 256 + h * 32 + a] * Wk[(size_t)(256 + d) * 256 + h * 32 + a];
        WqcatT[65536 + id] = (bf16)(s * SCALE);
        return;
    }
    if (blockIdx.x < 5888) {
        int id = (blockIdx.x - 5376) * 256 + t;
        int r2 = id >> 8, col = id & 255;
        int h = r2 >> 6, d = r2 & 63;
        float s = 0.f;
        #pragma unroll
        for (int a = 0; a < 32; ++a)
            s += Wv[(size_t)(256 + d) * 256 + h * 32 + a] * Wo[(size_t)(h * 32 + a) * 256 + col];
        WstackT[(size_t)col * 768 + 256 + r2] = (bf16)s;
        return;
    }
    if (blockIdx.x == 5888) {
        #pragma unroll
        for (int rep = 0; rep < 3; ++rep) {
            int idx = rep * 256 + t;
            if (idx >= 768) break;
            float s;
            if (idx < 256) s = bq[idx];
            else {
                int hd = idx - 256, h = hd >> 6, d = hd & 63;
                s = 0.f;
                #pragma unroll
                for (int a = 0; a < 32; ++a)
                    s += bq[h * 32 + a] * Wk[(size_t)(256 + d) * 256 + h * 32 + a];
            }
            bqcat[idx] = s * SCALE;
        }
        return;
    }
    {   // biaso = bo + bv @ Wo
        float s = bo[t];
        for (int u = 0; u < 256; ++u) s += bv[u] * Wo[(size_t)u * 256 + t];
        biaso[t] = s;
    }
}

// ---------------------------------------------------------------------------
// Attention: r15 structure + q/qproj loads hoisted BEFORE the first barrier
// (they depend only on n, not s_s — overlap dist staging + barrier drain).
// ---------------------------------------------------------------------------
__global__ __launch_bounds__(256) void attn_kernel(
    const bf16* __restrict__ qcat,      // [NN, 768]  (q | qproj), pre-scaled
    const bf16* __restrict__ localKV,   // [NN, 512]  (K | V)
    const float* __restrict__ dist,     // [NN, 16, 64]
    const int*  __restrict__ structure, // [NN, 16]
    bf16* __restrict__ concat)          // [NN, 768]
{
    const int n = blockIdx.x;
    const int t = threadIdx.x;
    const int h = t >> 5, j = (t >> 1) & 15, part = t & 1;

    __shared__ float dist_s[16][68];   // 272B rows: 16B-aligned for b128 ops
    __shared__ bf16  V_s[16][264];
    __shared__ float attn_s[8][16];
    __shared__ int   s_s[16];

    // ---- q/qproj loads: independent of s_s — issue FIRST, consume after barrier
    const bf16* qp_q = qcat + (size_t)n * 768 + h * 32 + part * 16;
    bf16x8 qa = *(const bf16x8*)qp_q;
    bf16x8 qb = *(const bf16x8*)(qp_q + 8);
    const bf16* qp_p = qcat + (size_t)n * 768 + 256 + h * 64 + part * 32;
    bf16x8 p[4];
    p[0] = *(const bf16x8*)qp_p;
    p[1] = *(const bf16x8*)(qp_p + 8);
    p[2] = *(const bf16x8*)(qp_p + 16);
    p[3] = *(const bf16x8*)(qp_p + 24);

    {   // dist staging: thread t covers floats [4t, 4t+4)  (coalesced 16B)
        const float* dp = dist + (size_t)n * (KNBR * DISTD);
        float4 dv4 = ((const float4*)dp)[t];
        f32x4 w4; w4[0] = dv4.x; w4[1] = dv4.y; w4[2] = dv4.z; w4[3] = dv4.w;
        *(f32x4*)&dist_s[t >> 4][(t & 15) * 4] = w4;
    }
    if (t < 16) s_s[t] = structure[(size_t)n * KNBR + t];
    __syncthreads();

    #pragma unroll
    for (int pass = 0; pass < 2; ++pass) {
        int idx = pass * 256 + t;
        int row = idx >> 5, chunk = idx & 31;
        bf16x8 v = *(const bf16x8*)(localKV + (size_t)s_s[row] * 512 + 256 + chunk * 8);
        *(bf16x8*)&V_s[row][chunk * 8] = v;
    }

    const bf16* kp = localKV + (size_t)s_s[j] * 512 + h * 32 + part * 16;
    bf16x8 ka = *(const bf16x8*)kp;
    bf16x8 kb = *(const bf16x8*)(kp + 8);

    float sc = 0.f;
#if __has_builtin(__builtin_amdgcn_fdot2_f32_bf16)
    {
        const bf16x2* qa2 = (const bf16x2*)&qa;
        const bf16x2* qb2 = (const bf16x2*)&qb;
        const bf16x2* ka2 = (const bf16x2*)&ka;
        const bf16x2* kb2 = (const bf16x2*)&kb;
        #pragma unroll
        for (int i = 0; i < 4; ++i)
            sc = __builtin_amdgcn_fdot2_f32_bf16(qa2[i], ka2[i], sc, false);
        #pragma unroll
        for (int i = 0; i < 4; ++i)
            sc = __builtin_amdgcn_fdot2_f32_bf16(qb2[i], kb2[i], sc, false);
    }
#else
    #pragma unroll
    for (int i = 0; i < 8; ++i)
        sc += (float)qa[i] * (float)ka[i] + (float)qb[i] * (float)kb[i];
#endif

    const int dbase = part * 32;
    #pragma unroll
    for (int i = 0; i < 4; ++i) {
        const f32x4 a4 = *(const f32x4*)&dist_s[j][dbase + 8 * i];
        const f32x4 b4 = *(const f32x4*)&dist_s[j][dbase + 8 * i + 4];
        sc += a4[0] * (float)p[i][0] + a4[1] * (float)p[i][1]
            + a4[2] * (float)p[i][2] + a4[3] * (float)p[i][3]
            + b4[0] * (float)p[i][4] + b4[1] * (float)p[i][5]
            + b4[2] * (float)p[i][6] + b4[3] * (float)p[i][7];
    }

    sc += __shfl_xor(sc, 1);           // full (pre-scaled) score
    float m = sc;
    m = fmaxf(m, __shfl_xor(m, 2));
    m = fmaxf(m, __shfl_xor(m, 4));
    m = fmaxf(m, __shfl_xor(m, 8));
    m = fmaxf(m, __shfl_xor(m, 16));
    float e = __expf(sc - m);
    float sum = e;
    sum += __shfl_xor(sum, 2);
    sum += __shfl_xor(sum, 4);
    sum += __shfl_xor(sum, 8);
    sum += __shfl_xor(sum, 16);
    float attn = e / sum;
    if (!part) attn_s[h][j] = attn;
    __syncthreads();

    if (t < 128) {
        const int c0 = t * 2;
        const int hh = t >> 4;
        float a0 = 0.f, a1 = 0.f;
        #pragma unroll
        for (int j2 = 0; j2 < 16; ++j2) {
            float wgt = attn_s[hh][j2];
            bf16x2 pv = *(const bf16x2*)&V_s[j2][c0];
            a0 += wgt * (float)pv[0];
            a1 += wgt * (float)pv[1];
        }
        bf16x2 o2; o2[0] = (bf16)a0; o2[1] = (bf16)a1;
        *(bf16x2*)&concat[(size_t)n * 768 + c0] = o2;
    } else {
        const int u = t - 128;
        const int base = u * 4;
        const int h3 = u >> 4, d3 = (u & 15) * 4;
        f32x4 acc4 = {};
        #pragma unroll
        for (int j2 = 0; j2 < 16; ++j2) {
            float wgt = attn_s[h3][j2];
            const f32x4 dv = *(const f32x4*)&dist_s[j2][d3];
            acc4 += wgt * dv;
        }
        bf16x4 o4;
        #pragma unroll
        for (int i = 0; i < 4; ++i) o4[i] = (bf16)acc4[i];
        *(bf16x4*)&concat[(size_t)n * 768 + 256 + base] = o4;
    }
}

// ---------------------------------------------------------------------------
extern "C" void kernel_launch(void* const* d_in, const int* in_sizes, int n_in,
                              void* d_out, int out_size, void* d_ws, size_t ws_size,
                              hipStream_t stream)
{
    const float* features = (const float*)d_in[0];
    const float* dist     = (const float*)d_in[1];
    const int*   structure= (const int*)d_in[2];
    const float* W0 = (const float*)d_in[3];
    const float* b0 = (const float*)d_in[4];
    const float* W1 = (const float*)d_in[5];
    const float* b1 = (const float*)d_in[6];
    const float* W2 = (const float*)d_in[7];
    const float* b2 = (const float*)d_in[8];
    const float* Wq = (const float*)d_in[9];
    const float* bq = (const float*)d_in[10];
    const float* Wk = (const float*)d_in[11];
    // d_in[12] = bk : dropped exactly (softmax-invariant per-head shift)
    const float* Wv = (const float*)d_in[13];
    const float* bv = (const float*)d_in[14];
    const float* Wo = (const float*)d_in[15];
    const float* bo = (const float*)d_in[16];
    float* out = (float*)d_out;

    const size_t MB = 1u << 20;
    char* w = (char*)d_ws;
    // live intervals:
    bf16*  fbf     = (bf16*)(w + 0 * MB);    // [0,8)    prep -> g1qcat
    bf16*  local_b = (bf16*)(w + 0 * MB);    // [0,8)    G3 -> KV     (fbf dead)
    bf16*  localKV = (bf16*)(w + 8 * MB);    // [8,24)   KV -> attn
    bf16*  H0      = (bf16*)(w + 16 * MB);   // [16,32)  g1qcat -> G2 (pre-KV)
    bf16*  qcat    = (bf16*)(w + 32 * MB);   // [32,56)  g1qcat -> attn
    bf16*  H1      = (bf16*)(w + 56 * MB);   // [56,72)  G2 -> G3
    bf16*  concat  = (bf16*)(w + 56 * MB);   // [56,80)  attn -> final (H1 dead)
    char*  wb      = w + 80 * MB;            // weights: prep -> final
    bf16*  W0T     = (bf16*)(wb + 0);
    bf16*  W1T     = (bf16*)(wb + 262144);
    bf16*  W2T     = (bf16*)(wb + 786432);
    bf16*  WkvT    = (bf16*)(wb + 1048576);
    bf16*  WqcatT  = (bf16*)(wb + 1310720);
    bf16*  WstackT = (bf16*)(wb + 1703936);
    float* bqcat   = (float*)(wb + 2097152);
    float* biaso   = (float*)(wb + 2100224);

    dim3 blk(256);

    prep_all<<<dim3(5890), blk, 0, stream>>>(
        features, W0, W1, W2, Wq, bq, Wk, Wv, Wo, bo, bv,
        fbf, W0T, W1T, W2T, WkvT, WqcatT, WstackT, bqcat, biaso);

    // fused: H0 = relu(relu(f)@W0+b0) [relu-in-frag]; qcat = f@Wqcat+bqcat
    g1qcat_kernel<<<dim3(10, 128), blk, 0, stream>>>(
        fbf, W0T, b0, WqcatT, bqcat, H0, qcat);

    // W1: H1 = relu(H0@W1+b1)          (BK=64: 512 blocks, 2/CU)
    gemm128<true,  true,  false, bf16, 2><<<dim3(4, 128), blk, 0, stream>>>(
        H0, W1T, b1, nullptr, H1, NN, 512, 512);
    // W2: local = relu(H1@W2+b2)       (256 blocks)
    gemm128<true,  true,  false, bf16, 2><<<dim3(2, 128), blk, 0, stream>>>(
        H1, W2T, b2, nullptr, local_b, NN, 256, 512);
    // KV: localKV = local @ [Wk|Wv]    (512 blocks)
    gemm128<false, false, false, bf16, 2><<<dim3(4, 128), blk, 0, stream>>>(
        local_b, WkvT, nullptr, nullptr, localKV, NN, 512, 256);

    attn_kernel<<<dim3(NN), blk, 0, stream>>>(
        qcat, localKV, dist, structure, concat);

    // out = concat @ [Wo ; U] + (bo + bv@Wo) + features  (256 blocks)
    gemm128<true,  false, true,  float, 2><<<dim3(2, 128), blk, 0, stream>>>(
        concat, WstackT, biaso, features, out, NN, 256, 768);
}